// Round 7
// baseline (215.714 us; speedup 1.0000x reference)
//
#include <hip/hip_runtime.h>

#define N_NODES 10000
#define CH 128
#define N_EDGES 320000
#define CAP 128    // LDS bucket capacity; deg ~ Binomial(640k,1e-4): mean 64, sigma 8
#define NPB 40     // nodes owned per block
#define NBLK 250   // 250 * 40 = 10000
#define TPB 512    // 8 waves -> 2 waves/SIMD (one block per CU)

// ---------------------------------------------------------------------------
// Structure: no global adjacency, no global atomics, no memset.
//   dispatch 1: x (fp32) -> xb (bf16)  [2.56 MB, L2-resident working set]
//   dispatch 2: mega-kernel, block owns 40 nodes:
//     A) scan full edge list (L2 broadcast), bin own-node endpoints into
//        LDS buckets with LDS atomics
//     B) gather neighbor bf16 rows -> fp32 means in LDS
//     C) dual GEMM + ReLU from LDS
// Workspace: only xb (2.56 MB).
// ---------------------------------------------------------------------------

__device__ __forceinline__ unsigned short f2bf(float f) {
    unsigned u = __float_as_uint(f);
    return (unsigned short)((u + 0x7FFFu + ((u >> 16) & 1u)) >> 16);  // RNE
}
__device__ __forceinline__ float bf2f(unsigned short h) {
    return __uint_as_float(((unsigned)h) << 16);
}

// Dispatch 1: convert 8 elements per thread. 625 x 256 x 8 = 1,280,000 exact.
__global__ __launch_bounds__(256) void convert_kernel(const float* __restrict__ x,
                                                      unsigned short* __restrict__ xb)
{
    const int t = blockIdx.x * blockDim.x + threadIdx.x;
    const float4 c0 = ((const float4*)x)[2 * t];
    const float4 c1 = ((const float4*)x)[2 * t + 1];
    ushort4 o0, o1;
    o0.x = f2bf(c0.x); o0.y = f2bf(c0.y); o0.z = f2bf(c0.z); o0.w = f2bf(c0.w);
    o1.x = f2bf(c1.x); o1.y = f2bf(c1.y); o1.z = f2bf(c1.z); o1.w = f2bf(c1.w);
    ((ushort4*)xb)[2 * t]     = o0;
    ((ushort4*)xb)[2 * t + 1] = o1;
}

// Dispatch 2: the mega-kernel.
__global__ __launch_bounds__(TPB) void mega_kernel(
    const float* __restrict__ x,
    const unsigned short* __restrict__ xb,
    const int* __restrict__ ei,
    const float* __restrict__ w,
    const float* __restrict__ b,
    float* __restrict__ out)
{
    __shared__ unsigned short bucket[NPB][CAP];  // 10 KB
    __shared__ int   cnt[NPB];
    __shared__ float sh_a[NPB][CH];              // 20 KB
    __shared__ float sh_x[NPB][CH];              // 20 KB

    const int tid = threadIdx.x;
    const int lo  = blockIdx.x * NPB;

    // ---- Phase A: scan all edges, bin own-range endpoints into LDS --------
    if (tid < NPB) cnt[tid] = 0;
    __syncthreads();

    const int4* e4 = (const int4*)ei;            // 2 edges per int4
    for (int t = tid; t < N_EDGES / 2; t += TPB) {
        const int4 p = e4[t];
        {   const unsigned r = (unsigned)(p.x - lo);
            if (r < NPB) { const int s = atomicAdd(&cnt[r], 1);
                           if (s < CAP) bucket[r][s] = (unsigned short)p.y; } }
        {   const unsigned r = (unsigned)(p.y - lo);
            if (r < NPB) { const int s = atomicAdd(&cnt[r], 1);
                           if (s < CAP) bucket[r][s] = (unsigned short)p.x; } }
        {   const unsigned r = (unsigned)(p.z - lo);
            if (r < NPB) { const int s = atomicAdd(&cnt[r], 1);
                           if (s < CAP) bucket[r][s] = (unsigned short)p.w; } }
        {   const unsigned r = (unsigned)(p.w - lo);
            if (r < NPB) { const int s = atomicAdd(&cnt[r], 1);
                           if (s < CAP) bucket[r][s] = (unsigned short)p.z; } }
    }

    // stage own x rows for the x@b^T term (1280 float4 over 512 threads)
    {
        const float4* xs = (const float4*)(x + (size_t)lo * CH);
        float4* sx = (float4*)sh_x;
        sx[tid] = xs[tid];
        sx[tid + TPB] = xs[tid + TPB];
        if (tid < NPB * CH / 4 - 2 * TPB) sx[tid + 2 * TPB] = xs[tid + 2 * TPB];
    }
    __syncthreads();

    // ---- Phase B: gather bf16 neighbor rows -> fp32 means in sh_a ---------
    // wave wv handles nodes wv, wv+8, ..., wv+32 (5 each). lane = 32h+l:
    // half h pulls neighbor 2*it+h; l spans the 256 B bf16 row as ushort4.
    {
        const int wv   = tid >> 6;
        const int lane = tid & 63;
        const int h    = lane >> 5;
        const int l    = lane & 31;
#pragma unroll
        for (int q = 0; q < 5; ++q) {
            const int ln  = wv + 8 * q;
            const int deg = cnt[ln];
            const int d   = deg < CAP ? deg : CAP;

            float4 acc = {0.f, 0.f, 0.f, 0.f};
            const int nit = (d + 1) >> 1;
#pragma unroll 4
            for (int it = 0; it < nit; ++it) {
                const int idx = 2 * it + h;          // < CAP always
                int j = bucket[ln][idx];             // garbage if idx>=d (masked)
                j = j < N_NODES ? j : 0;
                const ushort4 u = ((const ushort4*)(xb + (size_t)j * CH))[l];
                const float m = idx < d ? 1.0f : 0.0f;
                acc.x += m * bf2f(u.x);
                acc.y += m * bf2f(u.y);
                acc.z += m * bf2f(u.z);
                acc.w += m * bf2f(u.w);
            }
            acc.x += __shfl_xor(acc.x, 32, 64);
            acc.y += __shfl_xor(acc.y, 32, 64);
            acc.z += __shfl_xor(acc.z, 32, 64);
            acc.w += __shfl_xor(acc.w, 32, 64);
            if (h == 0) {
                const float inv = deg > 0 ? 1.0f / (float)deg : 0.0f;
                float4 o4;
                o4.x = acc.x * inv; o4.y = acc.y * inv;
                o4.z = acc.z * inv; o4.w = acc.w * inv;
                ((float4*)sh_a[ln])[l] = o4;
            }
        }
    }
    __syncthreads();

    // ---- Phase C: out = relu(sh_a @ w^T + sh_x @ b^T) ----------------------
    // thread (g,o): g in 0..3 handles nodes g*10..g*10+9, out channel o.
    // LDS reads are wave-uniform broadcasts (conflict-free).
    {
        const int o = tid & 127;
        const int g = tid >> 7;
        const float4* wr = (const float4*)(w + (size_t)o * CH);
        const float4* br = (const float4*)(b + (size_t)o * CH);

        float acc[10];
#pragma unroll
        for (int n = 0; n < 10; ++n) acc[n] = 0.f;

        for (int k = 0; k < CH / 4; ++k) {
            const float4 wv4 = wr[k];
            const float4 bv4 = br[k];
#pragma unroll
            for (int n = 0; n < 10; ++n) {
                const float4 a4 = ((const float4*)sh_a[g * 10 + n])[k];
                const float4 x4 = ((const float4*)sh_x[g * 10 + n])[k];
                acc[n] += a4.x * wv4.x + a4.y * wv4.y + a4.z * wv4.z + a4.w * wv4.w
                        + x4.x * bv4.x + x4.y * bv4.y + x4.z * bv4.z + x4.w * bv4.w;
            }
        }
#pragma unroll
        for (int n = 0; n < 10; ++n) {
            const int node = lo + g * 10 + n;
            const float v = acc[n];
            out[(size_t)node * CH + o] = v > 0.f ? v : 0.f;
        }
    }
}

// ---------------------------------------------------------------------------
extern "C" void kernel_launch(void* const* d_in, const int* in_sizes, int n_in,
                              void* d_out, int out_size, void* d_ws, size_t ws_size,
                              hipStream_t stream)
{
    const float* x  = (const float*)d_in[0];
    const int*   ei = (const int*)d_in[1];   // (E,2) int32
    const float* w  = (const float*)d_in[2];
    const float* b  = (const float*)d_in[3];
    float*       out = (float*)d_out;

    unsigned short* xb = (unsigned short*)d_ws;   // 2.56 MB

    convert_kernel<<<625, 256, 0, stream>>>(x, xb);
    mega_kernel<<<NBLK, TPB, 0, stream>>>(x, xb, ei, w, b, out);
}

// Round 8
// 203.260 us; speedup vs baseline: 1.0613x; 1.0613x over previous
//
#include <hip/hip_runtime.h>

#define N_NODES 10000
#define CH 128
#define N_EDGES 320000
#define CAP 128    // bucket capacity; deg ~ Binomial(640k,1e-4): mean 64, sigma 8
#define NPB 8      // nodes per block in gather+gemm
#define GG_BLOCKS 1250   // 1250 * 8 = 10000 exactly

// ---------------------------------------------------------------------------
// Workspace layout (d_ws), total 5.16 MB:
//   int    cursor[N_NODES]       // degree counters (memset 0, 40 KB)
//   ushort adj   [N_NODES*CAP]   // bucketed adjacency  @ 40000   (2.56 MB)
//   ushort xb    [N_NODES*CH]    // x in bf16           @ 2600000 (2.56 MB)
// ---------------------------------------------------------------------------

__device__ __forceinline__ unsigned short f2bf(float f) {
    unsigned u = __float_as_uint(f);
    return (unsigned short)((u + 0x7FFFu + ((u >> 16) & 1u)) >> 16);  // RNE
}
__device__ __forceinline__ float bf2f(unsigned short h) {
    return __uint_as_float(((unsigned)h) << 16);
}

// Kernel 1: bucket fill (2 edges/thread) + x->bf16 convert fused in
// (independent work overlapping atomic latency). 625 blocks x 256 threads.
__global__ __launch_bounds__(256) void fill_convert_kernel(
    const int* __restrict__ ei,
    const float* __restrict__ x,
    int* __restrict__ cursor,
    unsigned short* __restrict__ adj,
    unsigned short* __restrict__ xb)
{
    const int t = blockIdx.x * blockDim.x + threadIdx.x;   // 0..159999

    // convert 8 elements of x to bf16
    const float4 c0 = ((const float4*)x)[2 * t];
    const float4 c1 = ((const float4*)x)[2 * t + 1];
    ushort4 o0, o1;
    o0.x = f2bf(c0.x); o0.y = f2bf(c0.y); o0.z = f2bf(c0.z); o0.w = f2bf(c0.w);
    o1.x = f2bf(c1.x); o1.y = f2bf(c1.y); o1.z = f2bf(c1.z); o1.w = f2bf(c1.w);
    ((ushort4*)xb)[2 * t]     = o0;
    ((ushort4*)xb)[2 * t + 1] = o1;

    // fill two edges (4 atomics in flight before any dependent store)
    const int4 p = ((const int4*)ei)[t];
    const bool v0 = (unsigned)p.x < N_NODES && (unsigned)p.y < N_NODES;
    const bool v1 = (unsigned)p.z < N_NODES && (unsigned)p.w < N_NODES;
    int s0 = 0, s1 = 0, s2 = 0, s3 = 0;
    if (v0) { s0 = atomicAdd(&cursor[p.x], 1); s1 = atomicAdd(&cursor[p.y], 1); }
    if (v1) { s2 = atomicAdd(&cursor[p.z], 1); s3 = atomicAdd(&cursor[p.w], 1); }
    if (v0) {
        if (s0 < CAP) adj[(size_t)p.x * CAP + s0] = (unsigned short)p.y;
        if (s1 < CAP) adj[(size_t)p.y * CAP + s1] = (unsigned short)p.x;
    }
    if (v1) {
        if (s2 < CAP) adj[(size_t)p.z * CAP + s2] = (unsigned short)p.w;
        if (s3 < CAP) adj[(size_t)p.w * CAP + s3] = (unsigned short)p.z;
    }
}

// Kernel 2: fused gather + dual GEMM + ReLU. 1250 blocks x 256 threads,
// 8 nodes/block (high occupancy: ~20 waves/CU).
// Gather: wave wv handles nodes 2wv+q (q=0,1); lane=32h+l, half h pulls
// neighbor 2*it+h, l spans the 256 B bf16 row as ushort4; unroll 4 -> 8 rows
// in flight per wave.
// GEMM: thread (ng,c) computes nodes {2ng,2ng+1} x channels {c,c+64}:
// per iter 4 LDS b128 + 4 global float4 feed 32 FMA (1:8 LDS:FMA).
__global__ __launch_bounds__(256) void gather_gemm_kernel(
    const float* __restrict__ x,
    const unsigned short* __restrict__ xb,
    const int* __restrict__ cursor,
    const unsigned short* __restrict__ adj,
    const float* __restrict__ w,
    const float* __restrict__ b,
    float* __restrict__ out)
{
    __shared__ float sh_a[NPB][CH];   // 4 KB
    __shared__ float sh_x[NPB][CH];   // 4 KB
    const int tid   = threadIdx.x;
    const int node0 = blockIdx.x * NPB;

    // stage own x rows (fp32, exact): 8 rows = 256 float4, one per thread
    ((float4*)sh_x)[tid] = ((const float4*)(x + (size_t)node0 * CH))[tid];

    {
        const int wv   = tid >> 6;
        const int lane = tid & 63;
        const int h    = lane >> 5;
        const int l    = lane & 31;
#pragma unroll
        for (int q = 0; q < 2; ++q) {
            const int ln   = 2 * wv + q;
            const int node = node0 + ln;
            const int deg  = cursor[node];
            const int d    = deg < CAP ? deg : CAP;
            const unsigned short* nb = adj + (size_t)node * CAP;

            float4 acc = {0.f, 0.f, 0.f, 0.f};
            const int nit = (d + 1) >> 1;
#pragma unroll 4
            for (int it = 0; it < nit; ++it) {
                const int idx = 2 * it + h;            // always < CAP
                int j = nb[idx];
                j = j < N_NODES ? j : 0;               // clamp stale garbage
                const ushort4 u = ((const ushort4*)(xb + (size_t)j * CH))[l];
                const float m = idx < d ? 1.0f : 0.0f;
                acc.x += m * bf2f(u.x);
                acc.y += m * bf2f(u.y);
                acc.z += m * bf2f(u.z);
                acc.w += m * bf2f(u.w);
            }
            acc.x += __shfl_xor(acc.x, 32, 64);
            acc.y += __shfl_xor(acc.y, 32, 64);
            acc.z += __shfl_xor(acc.z, 32, 64);
            acc.w += __shfl_xor(acc.w, 32, 64);
            if (h == 0) {
                const float inv = deg > 0 ? 1.0f / (float)deg : 0.0f;
                float4 o4;
                o4.x = acc.x * inv; o4.y = acc.y * inv;
                o4.z = acc.z * inv; o4.w = acc.w * inv;
                ((float4*)sh_a[ln])[l] = o4;
            }
        }
    }
    __syncthreads();

    // GEMM: c = tid&63 -> channels {c, c+64}; ng = tid>>6 -> nodes {2ng, 2ng+1}
    {
        const int c  = tid & 63;
        const int ng = tid >> 6;
        const int n0 = 2 * ng, n1 = 2 * ng + 1;

        const float4* A0 = (const float4*)sh_a[n0];
        const float4* A1 = (const float4*)sh_a[n1];
        const float4* X0 = (const float4*)sh_x[n0];
        const float4* X1 = (const float4*)sh_x[n1];
        const float4* w0 = (const float4*)(w + (size_t)c * CH);
        const float4* w1 = (const float4*)(w + (size_t)(c + 64) * CH);
        const float4* b0 = (const float4*)(b + (size_t)c * CH);
        const float4* b1 = (const float4*)(b + (size_t)(c + 64) * CH);

        float a00 = 0.f, a01 = 0.f, a10 = 0.f, a11 = 0.f;
#pragma unroll 2
        for (int k = 0; k < CH / 4; ++k) {
            const float4 wv0 = w0[k], wv1 = w1[k];
            const float4 bv0 = b0[k], bv1 = b1[k];
            const float4 q0 = A0[k], q1 = A1[k];
            const float4 y0 = X0[k], y1 = X1[k];
            a00 += q0.x * wv0.x + q0.y * wv0.y + q0.z * wv0.z + q0.w * wv0.w
                 + y0.x * bv0.x + y0.y * bv0.y + y0.z * bv0.z + y0.w * bv0.w;
            a01 += q0.x * wv1.x + q0.y * wv1.y + q0.z * wv1.z + q0.w * wv1.w
                 + y0.x * bv1.x + y0.y * bv1.y + y0.z * bv1.z + y0.w * bv1.w;
            a10 += q1.x * wv0.x + q1.y * wv0.y + q1.z * wv0.z + q1.w * wv0.w
                 + y1.x * bv0.x + y1.y * bv0.y + y1.z * bv0.z + y1.w * bv0.w;
            a11 += q1.x * wv1.x + q1.y * wv1.y + q1.z * wv1.z + q1.w * wv1.w
                 + y1.x * bv1.x + y1.y * bv1.y + y1.z * bv1.z + y1.w * bv1.w;
        }
        out[(size_t)(node0 + n0) * CH + c]      = a00 > 0.f ? a00 : 0.f;
        out[(size_t)(node0 + n0) * CH + c + 64] = a01 > 0.f ? a01 : 0.f;
        out[(size_t)(node0 + n1) * CH + c]      = a10 > 0.f ? a10 : 0.f;
        out[(size_t)(node0 + n1) * CH + c + 64] = a11 > 0.f ? a11 : 0.f;
    }
}

// ---------------------------------------------------------------------------
extern "C" void kernel_launch(void* const* d_in, const int* in_sizes, int n_in,
                              void* d_out, int out_size, void* d_ws, size_t ws_size,
                              hipStream_t stream)
{
    const float* x  = (const float*)d_in[0];
    const int*   ei = (const int*)d_in[1];   // (E,2) int32
    const float* w  = (const float*)d_in[2];
    const float* b  = (const float*)d_in[3];
    float*       out = (float*)d_out;

    int*            cursor = (int*)d_ws;                               // 40,000 B
    unsigned short* adj    = (unsigned short*)((char*)d_ws + 40000);   // 2,560,000 B
    unsigned short* xb     = (unsigned short*)((char*)d_ws + 2600000); // 2,560,000 B

    hipMemsetAsync(d_ws, 0, N_NODES * sizeof(int), stream);

    fill_convert_kernel<<<625, 256, 0, stream>>>(ei, x, cursor, adj, xb);
    gather_gemm_kernel<<<GG_BLOCKS, 256, 0, stream>>>(x, xb, cursor, adj, w, b, out);
}